// Round 12
// baseline (147.909 us; speedup 1.0000x reference)
//
#include <hip/hip_runtime.h>

#define NDIM 128
#define CAP  64   // per-node bucket capacity (mean degree 12, Poisson tail safe)

typedef __attribute__((ext_vector_type(8))) short bf16x8;
typedef __attribute__((ext_vector_type(4))) float f32x4;

__device__ __forceinline__ unsigned short bf16rne(float x) {
    unsigned u = __float_as_uint(x);
    unsigned r = (u + 0x7FFFu + ((u >> 16) & 1u)) >> 16;
    return (unsigned short)r;
}

// ---- fast zero for degs_i + cursor ----
__global__ __launch_bounds__(256) void zero_kernel(uint4* __restrict__ p, int n16)
{
    int i = blockIdx.x * 256 + threadIdx.x;
    if (i < n16) p[i] = make_uint4(0u, 0u, 0u, 0u);
}

// ---- fused prep: nodes->bf16 + W->bf16^T + sender histogram + bucket fill ----
__global__ __launch_bounds__(256) void prep_kernel(const float* __restrict__ nodes,
                                                   unsigned short* __restrict__ nbf,
                                                   const float* __restrict__ W,
                                                   unsigned short* __restrict__ wt_bf,
                                                   const int* __restrict__ senders,
                                                   const int* __restrict__ receivers,
                                                   int* __restrict__ degs_i,
                                                   int* __restrict__ cursor,
                                                   int* __restrict__ csr_src,
                                                   int n_grp8, int ne)
{
    int i = blockIdx.x * 256 + threadIdx.x;
    int ne4 = ne >> 2;
    int q = i / 5;
    bool doedge = ((i % 5) == 0) && (q < ne4);

    int4 s4, r4;
    if (doedge) {
        s4 = ((const int4*)senders)[q];
        r4 = ((const int4*)receivers)[q];
        atomicAdd(&degs_i[s4.x], 1);      // fire-and-forget
        atomicAdd(&degs_i[s4.y], 1);
        atomicAdd(&degs_i[s4.z], 1);
        atomicAdd(&degs_i[s4.w], 1);
    }

    if (i < n_grp8) {
        const float4* p = (const float4*)nodes + (size_t)i * 2;
        float4 a = p[0];
        float4 c = p[1];
        uint4 o;
        o.x = (unsigned)bf16rne(a.x) | ((unsigned)bf16rne(a.y) << 16);
        o.y = (unsigned)bf16rne(a.z) | ((unsigned)bf16rne(a.w) << 16);
        o.z = (unsigned)bf16rne(c.x) | ((unsigned)bf16rne(c.y) << 16);
        o.w = (unsigned)bf16rne(c.z) | ((unsigned)bf16rne(c.w) << 16);
        *(uint4*)(nbf + (size_t)i * 8) = o;
    }
    if (i < NDIM * NDIM) {           // Wt[c][k] = W[k][c], bf16
        int c = i >> 7, k = i & 127;
        wt_bf[i] = bf16rne(W[k * NDIM + c]);
    }

    if (doedge) {
        int p0 = atomicAdd(&cursor[r4.x], 1);
        int p1 = atomicAdd(&cursor[r4.y], 1);
        int p2 = atomicAdd(&cursor[r4.z], 1);
        int p3 = atomicAdd(&cursor[r4.w], 1);
        if (p0 < CAP) csr_src[(size_t)r4.x * CAP + p0] = s4.x;
        if (p1 < CAP) csr_src[(size_t)r4.y * CAP + p1] = s4.y;
        if (p2 < CAP) csr_src[(size_t)r4.z * CAP + p2] = s4.z;
        if (p3 < CAP) csr_src[(size_t)r4.w * CAP + p3] = s4.w;
    }
    if (i == 0) {
        for (int e = ne4 * 4; e < ne; ++e) {
            int s = senders[e];
            int r = receivers[e];
            atomicAdd(&degs_i[s], 1);
            int p = atomicAdd(&cursor[r], 1);
            if (p < CAP) csr_src[(size_t)r * CAP + p] = s;
        }
    }
}

// ---- fused gather + MFMA gemm ----
// Each wave: gathers 4 nodes (unroll-8 MLP body), parks the 4 bf16 rows in
// wave-private LDS (XOR-swizzled, conflict-free b128 reads), then computes
// out rows = agg @ W + swb*b via 16x16x32 MFMA with A rows duplicated mod-4.
// Only kg==0 lanes store (D rows 4-15 are duplicates).
__global__ __launch_bounds__(256, 6) void gg_kernel(const unsigned short* __restrict__ nbf,
                                                    const int* __restrict__ csr_src,
                                                    const int* __restrict__ degs_i,
                                                    const int* __restrict__ degr_i,
                                                    const unsigned short* __restrict__ wt_bf,
                                                    const float* __restrict__ b,
                                                    float* __restrict__ out, int n)
{
    __shared__ unsigned short alds[4][512];   // [wave][4 rows x 128 bf16], 4 KiB
    __shared__ float          swlds[4][4];

    int wid  = threadIdx.x >> 6;
    int lane = threadIdx.x & 63;
    int node0 = (blockIdx.x * 4 + wid) * 4;
    char* al = (char*)&alds[wid][0];

    const unsigned short* nb = nbf + (size_t)lane * 2;

    for (int r = 0; r < 4; ++r) {
        int node = node0 + r;
        float ax = 0.f, ay = 0.f, sw = 0.f;
        float ir = 0.f;
        if (node < n) {
            int d = degr_i[node];
            if (d > CAP) d = CAP;
            const int* bucket = csr_src + (size_t)node * CAP;
            int i = 0;
            for (; i + 8 <= d; i += 8) {
                int s0 = bucket[i + 0];
                int s1 = bucket[i + 1];
                int s2 = bucket[i + 2];
                int s3 = bucket[i + 3];
                int s4 = bucket[i + 4];
                int s5 = bucket[i + 5];
                int s6 = bucket[i + 6];
                int s7 = bucket[i + 7];
                float d0 = (float)degs_i[s0];
                float d1 = (float)degs_i[s1];
                float d2 = (float)degs_i[s2];
                float d3 = (float)degs_i[s3];
                float d4 = (float)degs_i[s4];
                float d5 = (float)degs_i[s5];
                float d6 = (float)degs_i[s6];
                float d7 = (float)degs_i[s7];
                unsigned u0 = *(const unsigned*)(nb + (size_t)s0 * NDIM);
                unsigned u1 = *(const unsigned*)(nb + (size_t)s1 * NDIM);
                unsigned u2 = *(const unsigned*)(nb + (size_t)s2 * NDIM);
                unsigned u3 = *(const unsigned*)(nb + (size_t)s3 * NDIM);
                unsigned u4 = *(const unsigned*)(nb + (size_t)s4 * NDIM);
                unsigned u5 = *(const unsigned*)(nb + (size_t)s5 * NDIM);
                unsigned u6 = *(const unsigned*)(nb + (size_t)s6 * NDIM);
                unsigned u7 = *(const unsigned*)(nb + (size_t)s7 * NDIM);
                float w0 = rsqrtf(fmaxf(d0, 1.0f));
                float w1 = rsqrtf(fmaxf(d1, 1.0f));
                float w2 = rsqrtf(fmaxf(d2, 1.0f));
                float w3 = rsqrtf(fmaxf(d3, 1.0f));
                float w4 = rsqrtf(fmaxf(d4, 1.0f));
                float w5 = rsqrtf(fmaxf(d5, 1.0f));
                float w6 = rsqrtf(fmaxf(d6, 1.0f));
                float w7 = rsqrtf(fmaxf(d7, 1.0f));
                ax = fmaf(w0, __uint_as_float(u0 << 16), ax);
                ay = fmaf(w0, __uint_as_float(u0 & 0xFFFF0000u), ay);
                ax = fmaf(w1, __uint_as_float(u1 << 16), ax);
                ay = fmaf(w1, __uint_as_float(u1 & 0xFFFF0000u), ay);
                ax = fmaf(w2, __uint_as_float(u2 << 16), ax);
                ay = fmaf(w2, __uint_as_float(u2 & 0xFFFF0000u), ay);
                ax = fmaf(w3, __uint_as_float(u3 << 16), ax);
                ay = fmaf(w3, __uint_as_float(u3 & 0xFFFF0000u), ay);
                ax = fmaf(w4, __uint_as_float(u4 << 16), ax);
                ay = fmaf(w4, __uint_as_float(u4 & 0xFFFF0000u), ay);
                ax = fmaf(w5, __uint_as_float(u5 << 16), ax);
                ay = fmaf(w5, __uint_as_float(u5 & 0xFFFF0000u), ay);
                ax = fmaf(w6, __uint_as_float(u6 << 16), ax);
                ay = fmaf(w6, __uint_as_float(u6 & 0xFFFF0000u), ay);
                ax = fmaf(w7, __uint_as_float(u7 << 16), ax);
                ay = fmaf(w7, __uint_as_float(u7 & 0xFFFF0000u), ay);
                sw += w0 + w1 + w2 + w3 + w4 + w5 + w6 + w7;
            }
            for (; i < d; ++i) {
                int s = bucket[i];
                float w = rsqrtf(fmaxf((float)degs_i[s], 1.0f));
                unsigned u = *(const unsigned*)(nb + (size_t)s * NDIM);
                ax = fmaf(w, __uint_as_float(u << 16), ax);
                ay = fmaf(w, __uint_as_float(u & 0xFFFF0000u), ay);
                sw += w;
            }
            ir = rsqrtf(fmaxf((float)degr_i[node], 1.0f));
        }
        unsigned pk = (unsigned)bf16rne(ax * ir) | ((unsigned)bf16rne(ay * ir) << 16);
        // swizzled LDS store: logical byte x of row r lives at x ^ (r<<4)
        *(unsigned*)(al + r * 256 + ((lane * 4) ^ (r << 4))) = pk;
        if (lane == 0) swlds[wid][r] = sw * ir;
    }
    __syncthreads();

    // ---- MFMA phase ----
    int l15 = lane & 15;
    int kg  = lane >> 4;            // 0..3
    int arow = l15 & 3;             // A rows duplicated mod 4

    bf16x8 afrag[4];
    #pragma unroll
    for (int kk = 0; kk < 4; ++kk) {
        int col0 = kg * 16 + kk * 64;               // byte offset within row
        afrag[kk] = *(const bf16x8*)(al + arow * 256 + (col0 ^ (arow << 4)));
    }

    float swr0 = swlds[wid][0];
    float swr1 = swlds[wid][1];
    float swr2 = swlds[wid][2];
    float swr3 = swlds[wid][3];

    #pragma unroll 2
    for (int c = 0; c < 8; ++c) {
        float bc = b[c * 16 + l15];
        f32x4 acc = { swr0 * bc, swr1 * bc, swr2 * bc, swr3 * bc };
        const unsigned short* bbase = wt_bf + (size_t)(c * 16 + l15) * NDIM + kg * 8;
        #pragma unroll
        for (int kk = 0; kk < 4; ++kk) {
            bf16x8 bfrag = *(const bf16x8*)(bbase + kk * 32);
            acc = __builtin_amdgcn_mfma_f32_16x16x32_bf16(afrag[kk], bfrag, acc, 0, 0, 0);
        }
        if (kg == 0) {                     // D rows 4-15 are duplicates of 0-3
            #pragma unroll
            for (int r = 0; r < 4; ++r) {
                int row = node0 + r;
                if (row < n) out[(size_t)row * NDIM + c * 16 + l15] = acc[r];
            }
        }
    }
}

extern "C" void kernel_launch(void* const* d_in, const int* in_sizes, int n_in,
                              void* d_out, int out_size, void* d_ws, size_t ws_size,
                              hipStream_t stream)
{
    const float* nodes     = (const float*)d_in[0];
    const int*   senders   = (const int*)d_in[1];
    const int*   receivers = (const int*)d_in[2];
    const float* W         = (const float*)d_in[3];
    const float* b         = (const float*)d_in[4];
    float*       out       = (float*)d_out;

    int n  = in_sizes[0] / NDIM;   // 50000
    int ne = in_sizes[1];          // 600000

    // ws layout: [degs_i n | cursor n | csr n*CAP | nbf n*128 | wt 128*128]
    int*            degs_i  = (int*)d_ws;
    int*            cursor  = degs_i + n;
    int*            csr_src = cursor + n;
    unsigned short* nbf     = (unsigned short*)(csr_src + (size_t)n * CAP);
    unsigned short* wt_bf   = nbf + (size_t)n * NDIM;

    int n16 = (int)(((size_t)2 * n * sizeof(int)) / 16);
    zero_kernel<<<(n16 + 255) / 256, 256, 0, stream>>>((uint4*)d_ws, n16);

    int n_grp8 = n * (NDIM / 8);                  // 800000 conversion groups
    long long need = n_grp8;
    long long edge_span = (long long)((ne >> 2)) * 5;
    if (edge_span > need) need = edge_span;
    int pb = (int)((need + 255) / 256);
    prep_kernel<<<pb, 256, 0, stream>>>(nodes, nbf, W, wt_bf, senders, receivers,
                                        degs_i, cursor, csr_src, n_grp8, ne);

    int gb = (n + 15) / 16;        // 16 nodes per block (4 waves x 4 nodes)
    gg_kernel<<<gb, 256, 0, stream>>>(nbf, csr_src, degs_i, cursor, wt_bf, b, out, n);
}

// Round 13
// 118.398 us; speedup vs baseline: 1.2493x; 1.2493x over previous
//
#include <hip/hip_runtime.h>

#define NDIM 128
#define CAP  64   // per-node bucket capacity (mean degree 12, Poisson tail safe)

typedef __attribute__((ext_vector_type(8))) short bf16x8;
typedef __attribute__((ext_vector_type(4))) float f32x4;

__device__ __forceinline__ unsigned short bf16rne(float x) {
    unsigned u = __float_as_uint(x);
    unsigned r = (u + 0x7FFFu + ((u >> 16) & 1u)) >> 16;
    return (unsigned short)r;
}

// ---- fast zero for degs_i + cursor ----
__global__ __launch_bounds__(256) void zero_kernel(uint4* __restrict__ p, int n16)
{
    int i = blockIdx.x * 256 + threadIdx.x;
    if (i < n16) p[i] = make_uint4(0u, 0u, 0u, 0u);
}

// ---- fused prep: nodes->bf16 + W->bf16^T + sender histogram + bucket fill ----
__global__ __launch_bounds__(256) void prep_kernel(const float* __restrict__ nodes,
                                                   unsigned short* __restrict__ nbf,
                                                   const float* __restrict__ W,
                                                   unsigned short* __restrict__ wt_bf,
                                                   const int* __restrict__ senders,
                                                   const int* __restrict__ receivers,
                                                   int* __restrict__ degs_i,
                                                   int* __restrict__ cursor,
                                                   int* __restrict__ csr_src,
                                                   int n_grp8, int ne)
{
    int i = blockIdx.x * 256 + threadIdx.x;
    int ne4 = ne >> 2;
    int q = i / 5;
    bool doedge = ((i % 5) == 0) && (q < ne4);

    int4 s4, r4;
    if (doedge) {
        s4 = ((const int4*)senders)[q];
        r4 = ((const int4*)receivers)[q];
        atomicAdd(&degs_i[s4.x], 1);      // fire-and-forget
        atomicAdd(&degs_i[s4.y], 1);
        atomicAdd(&degs_i[s4.z], 1);
        atomicAdd(&degs_i[s4.w], 1);
    }

    if (i < n_grp8) {
        const float4* p = (const float4*)nodes + (size_t)i * 2;
        float4 a = p[0];
        float4 c = p[1];
        uint4 o;
        o.x = (unsigned)bf16rne(a.x) | ((unsigned)bf16rne(a.y) << 16);
        o.y = (unsigned)bf16rne(a.z) | ((unsigned)bf16rne(a.w) << 16);
        o.z = (unsigned)bf16rne(c.x) | ((unsigned)bf16rne(c.y) << 16);
        o.w = (unsigned)bf16rne(c.z) | ((unsigned)bf16rne(c.w) << 16);
        *(uint4*)(nbf + (size_t)i * 8) = o;
    }
    if (i < NDIM * NDIM) {           // Wt[c][k] = W[k][c], bf16
        int c = i >> 7, k = i & 127;
        wt_bf[i] = bf16rne(W[k * NDIM + c]);
    }

    if (doedge) {
        int p0 = atomicAdd(&cursor[r4.x], 1);
        int p1 = atomicAdd(&cursor[r4.y], 1);
        int p2 = atomicAdd(&cursor[r4.z], 1);
        int p3 = atomicAdd(&cursor[r4.w], 1);
        if (p0 < CAP) csr_src[(size_t)r4.x * CAP + p0] = s4.x;
        if (p1 < CAP) csr_src[(size_t)r4.y * CAP + p1] = s4.y;
        if (p2 < CAP) csr_src[(size_t)r4.z * CAP + p2] = s4.z;
        if (p3 < CAP) csr_src[(size_t)r4.w * CAP + p3] = s4.w;
    }
    if (i == 0) {
        for (int e = ne4 * 4; e < ne; ++e) {
            int s = senders[e];
            int r = receivers[e];
            atomicAdd(&degs_i[s], 1);
            int p = atomicAdd(&cursor[r], 1);
            if (p < CAP) csr_src[(size_t)r * CAP + p] = s;
        }
    }
}

// ---- fused gather + MFMA, TLP-preserving ----
// 1024-thread block = 16 waves = 16 nodes, ONE node per wave (same 50000-wave
// TLP as the round-11 standalone gather). Rows land in a 4 KiB LDS tile with
// byte ^ ((row&15)<<4) swizzle (store: per-wave permutation, conflict-free;
// read: 2-way, free). After one barrier, waves 0..7 each compute one 16-col
// tile: 4 MFMA over the TRUE 16-row A tile (no duplication).
__global__ __launch_bounds__(1024) void gg2_kernel(const unsigned short* __restrict__ nbf,
                                                   const int* __restrict__ csr_src,
                                                   const int* __restrict__ degs_i,
                                                   const int* __restrict__ degr_i,
                                                   const unsigned short* __restrict__ wt_bf,
                                                   const float* __restrict__ b,
                                                   float* __restrict__ out, int n)
{
    __shared__ unsigned short alds[16 * 128];   // 16 rows x 128 bf16 = 4 KiB
    __shared__ float          swlds[16];

    int wid  = threadIdx.x >> 6;      // 0..15 = row = node within block
    int lane = threadIdx.x & 63;
    int node = blockIdx.x * 16 + wid;
    char* al = (char*)alds;

    const unsigned short* nb = nbf + (size_t)lane * 2;

    float ax = 0.f, ay = 0.f, sw = 0.f, ir = 0.f;
    if (node < n) {
        int d = degr_i[node];
        if (d > CAP) d = CAP;
        const int* bucket = csr_src + (size_t)node * CAP;
        int i = 0;
        for (; i + 8 <= d; i += 8) {
            int s0 = bucket[i + 0];
            int s1 = bucket[i + 1];
            int s2 = bucket[i + 2];
            int s3 = bucket[i + 3];
            int s4 = bucket[i + 4];
            int s5 = bucket[i + 5];
            int s6 = bucket[i + 6];
            int s7 = bucket[i + 7];
            float d0 = (float)degs_i[s0];
            float d1 = (float)degs_i[s1];
            float d2 = (float)degs_i[s2];
            float d3 = (float)degs_i[s3];
            float d4 = (float)degs_i[s4];
            float d5 = (float)degs_i[s5];
            float d6 = (float)degs_i[s6];
            float d7 = (float)degs_i[s7];
            unsigned u0 = *(const unsigned*)(nb + (size_t)s0 * NDIM);
            unsigned u1 = *(const unsigned*)(nb + (size_t)s1 * NDIM);
            unsigned u2 = *(const unsigned*)(nb + (size_t)s2 * NDIM);
            unsigned u3 = *(const unsigned*)(nb + (size_t)s3 * NDIM);
            unsigned u4 = *(const unsigned*)(nb + (size_t)s4 * NDIM);
            unsigned u5 = *(const unsigned*)(nb + (size_t)s5 * NDIM);
            unsigned u6 = *(const unsigned*)(nb + (size_t)s6 * NDIM);
            unsigned u7 = *(const unsigned*)(nb + (size_t)s7 * NDIM);
            float w0 = rsqrtf(fmaxf(d0, 1.0f));
            float w1 = rsqrtf(fmaxf(d1, 1.0f));
            float w2 = rsqrtf(fmaxf(d2, 1.0f));
            float w3 = rsqrtf(fmaxf(d3, 1.0f));
            float w4 = rsqrtf(fmaxf(d4, 1.0f));
            float w5 = rsqrtf(fmaxf(d5, 1.0f));
            float w6 = rsqrtf(fmaxf(d6, 1.0f));
            float w7 = rsqrtf(fmaxf(d7, 1.0f));
            ax = fmaf(w0, __uint_as_float(u0 << 16), ax);
            ay = fmaf(w0, __uint_as_float(u0 & 0xFFFF0000u), ay);
            ax = fmaf(w1, __uint_as_float(u1 << 16), ax);
            ay = fmaf(w1, __uint_as_float(u1 & 0xFFFF0000u), ay);
            ax = fmaf(w2, __uint_as_float(u2 << 16), ax);
            ay = fmaf(w2, __uint_as_float(u2 & 0xFFFF0000u), ay);
            ax = fmaf(w3, __uint_as_float(u3 << 16), ax);
            ay = fmaf(w3, __uint_as_float(u3 & 0xFFFF0000u), ay);
            ax = fmaf(w4, __uint_as_float(u4 << 16), ax);
            ay = fmaf(w4, __uint_as_float(u4 & 0xFFFF0000u), ay);
            ax = fmaf(w5, __uint_as_float(u5 << 16), ax);
            ay = fmaf(w5, __uint_as_float(u5 & 0xFFFF0000u), ay);
            ax = fmaf(w6, __uint_as_float(u6 << 16), ax);
            ay = fmaf(w6, __uint_as_float(u6 & 0xFFFF0000u), ay);
            ax = fmaf(w7, __uint_as_float(u7 << 16), ax);
            ay = fmaf(w7, __uint_as_float(u7 & 0xFFFF0000u), ay);
            sw += w0 + w1 + w2 + w3 + w4 + w5 + w6 + w7;
        }
        for (; i < d; ++i) {
            int s = bucket[i];
            float w = rsqrtf(fmaxf((float)degs_i[s], 1.0f));
            unsigned u = *(const unsigned*)(nb + (size_t)s * NDIM);
            ax = fmaf(w, __uint_as_float(u << 16), ax);
            ay = fmaf(w, __uint_as_float(u & 0xFFFF0000u), ay);
            sw += w;
        }
        ir = rsqrtf(fmaxf((float)degr_i[node], 1.0f));
    }
    unsigned pk = (unsigned)bf16rne(ax * ir) | ((unsigned)bf16rne(ay * ir) << 16);
    *(unsigned*)(al + wid * 256 + ((lane * 4) ^ (wid << 4))) = pk;
    if (lane == 0) swlds[wid] = sw * ir;
    __syncthreads();

    // ---- MFMA phase: waves 0..7, one 16-col tile each ----
    if (wid < 8) {
        int c   = wid;
        int l15 = lane & 15;
        int kg  = lane >> 4;          // 0..3

        bf16x8 afrag[4];
        #pragma unroll
        for (int kk = 0; kk < 4; ++kk) {
            int off = (kk * 64 + kg * 16) ^ (l15 << 4);   // swizzled, 16B-aligned
            afrag[kk] = *(const bf16x8*)(al + l15 * 256 + off);
        }

        float s0 = swlds[kg * 4 + 0];
        float s1 = swlds[kg * 4 + 1];
        float s2 = swlds[kg * 4 + 2];
        float s3 = swlds[kg * 4 + 3];
        float bc = b[c * 16 + l15];
        f32x4 acc = { s0 * bc, s1 * bc, s2 * bc, s3 * bc };

        const unsigned short* bbase = wt_bf + (size_t)(c * 16 + l15) * NDIM + kg * 8;
        #pragma unroll
        for (int kk = 0; kk < 4; ++kk) {
            bf16x8 bfrag = *(const bf16x8*)(bbase + kk * 32);
            acc = __builtin_amdgcn_mfma_f32_16x16x32_bf16(afrag[kk], bfrag, acc, 0, 0, 0);
        }

        int rbase = blockIdx.x * 16 + kg * 4;
        #pragma unroll
        for (int r = 0; r < 4; ++r) {
            int row = rbase + r;
            if (row < n) out[(size_t)row * NDIM + c * 16 + l15] = acc[r];
        }
    }
}

extern "C" void kernel_launch(void* const* d_in, const int* in_sizes, int n_in,
                              void* d_out, int out_size, void* d_ws, size_t ws_size,
                              hipStream_t stream)
{
    const float* nodes     = (const float*)d_in[0];
    const int*   senders   = (const int*)d_in[1];
    const int*   receivers = (const int*)d_in[2];
    const float* W         = (const float*)d_in[3];
    const float* b         = (const float*)d_in[4];
    float*       out       = (float*)d_out;

    int n  = in_sizes[0] / NDIM;   // 50000
    int ne = in_sizes[1];          // 600000

    // ws layout: [degs_i n | cursor n | csr n*CAP | nbf n*128 | wt 128*128]
    int*            degs_i  = (int*)d_ws;
    int*            cursor  = degs_i + n;
    int*            csr_src = cursor + n;
    unsigned short* nbf     = (unsigned short*)(csr_src + (size_t)n * CAP);
    unsigned short* wt_bf   = nbf + (size_t)n * NDIM;

    int n16 = (int)(((size_t)2 * n * sizeof(int)) / 16);
    zero_kernel<<<(n16 + 255) / 256, 256, 0, stream>>>((uint4*)d_ws, n16);

    int n_grp8 = n * (NDIM / 8);                  // 800000 conversion groups
    long long need = n_grp8;
    long long edge_span = (long long)((ne >> 2)) * 5;
    if (edge_span > need) need = edge_span;
    int pb = (int)((need + 255) / 256);
    prep_kernel<<<pb, 256, 0, stream>>>(nodes, nbf, W, wt_bf, senders, receivers,
                                        degs_i, cursor, csr_src, n_grp8, ne);

    int gb = (n + 15) / 16;        // 16 nodes per block (16 waves x 1 node)
    gg2_kernel<<<gb, 1024, 0, stream>>>(nbf, csr_src, degs_i, cursor, wt_bf, b, out, n);
}